// Round 12
// baseline (239.531 us; speedup 1.0000x reference)
//
#include <hip/hip_runtime.h>
#include <hip/hip_bf16.h>

#define NNODES 20000
#define NEDGES 500000
#define LRELU(v) ((v) > 0.f ? (v) : (v) * 0.01f)

using bf16_t = __hip_bfloat16;
typedef unsigned short u16;
typedef unsigned int u32;
typedef __attribute__((ext_vector_type(8))) short bf16x8;  // 8 bf16 (4 VGPRs)
typedef __attribute__((ext_vector_type(4))) float f32x4;

__device__ inline float bf2f(short u) {
  u32 i = ((u32)(u16)u) << 16;
  float f;
  __builtin_memcpy(&f, &i, 4);
  return f;
}

// block-count constants
constexpr int NB = 128;                              // hist chunks per etype
constexpr int CHUNKE = (NEDGES + NB - 1) / NB;       // 3907 edges per hist block
constexpr int HB = (NEDGES + 255) / 256;             // scatter blocks per etype
constexpr int GB = (NNODES + 63) / 64;               // gemm blocks per etype
// 1024-thread split block counts
constexpr int SBX = NNODES * 128 / 4 / 1024;         // 625
constexpr int SBW1 = 128 * 128 / 4 / 1024;           // 4
constexpr int SBW2 = 64 * 128 / 4 / 1024;            // 2

// ---------------------------------------------------------------------------
// L1: LDS chunk histogram, 2*NB blocks (one per CU). pos[i] = rank within
// (chunk, dst). cnt[t][c][dst] = chunk count. No global atomics.
// ---------------------------------------------------------------------------
__global__ __launch_bounds__(1024) void k_hist(const int* __restrict__ dst0,
                                               const int* __restrict__ dst1,
                                               u16* __restrict__ cnt,
                                               u16* __restrict__ pos0,
                                               u16* __restrict__ pos1) {
  __shared__ u32 hist[NNODES / 2];  // 2 x u16 packed per word
  int b = blockIdx.x;
  int t = b >> 7, c = b & 127;      // NB = 128
  const int* dst = t ? dst1 : dst0;
  u16* pos = t ? pos1 : pos0;
  u16* cb = cnt + (size_t)(t * NB + c) * NNODES;
  int tid = threadIdx.x;

  for (int i = tid; i < NNODES / 2; i += 1024) hist[i] = 0;
  __syncthreads();

  int beg = c * CHUNKE, end = min(NEDGES, beg + CHUNKE);
  for (int i = beg + tid; i < end; i += 1024) {
    int d = dst[i];
    int sh = (d & 1) * 16;
    u32 old = atomicAdd(&hist[d >> 1], 1u << sh);
    pos[i] = (u16)((old >> sh) & 0xFFFFu);  // rank within (chunk, dst)
  }
  __syncthreads();

  for (int i = tid; i < NNODES / 2; i += 1024)
    *(u32*)&cb[2 * i] = hist[i];  // two u16 counts per 4B store
}

// ---------------------------------------------------------------------------
// L2a: combine. One thread per (t,dst): exclusive prefix over the NB chunk
// counts (written back into cnt as bases); total -> deg. All coalesced.
// ---------------------------------------------------------------------------
__global__ __launch_bounds__(256) void k_combine(u16* __restrict__ cnt,
                                                 int* __restrict__ deg) {
  int i = blockIdx.x * 256 + threadIdx.x;  // i in [0, 2*NNODES)
  if (i >= 2 * NNODES) return;
  int t = i / NNODES, dd = i - t * NNODES;
  int run = 0;
#pragma unroll 8
  for (int g = 0; g < NB; ++g) {
    size_t idx = (size_t)(t * NB + g) * NNODES + dd;
    int cv = cnt[idx];
    cnt[idx] = (u16)run;
    run += cv;
  }
  deg[i] = run;
}

// ---------------------------------------------------------------------------
// split body (1024-thread blocks)
// ---------------------------------------------------------------------------
__device__ inline void split_body(const float* in, bf16_t* hi, bf16_t* lo,
                                  int i, int n4) {
  if (i >= n4) return;
  float4 v = *(const float4*)&in[i * 4];
  bf16_t h0 = __float2bfloat16(v.x), h1 = __float2bfloat16(v.y);
  bf16_t h2 = __float2bfloat16(v.z), h3 = __float2bfloat16(v.w);
  hi[i * 4 + 0] = h0;
  hi[i * 4 + 1] = h1;
  hi[i * 4 + 2] = h2;
  hi[i * 4 + 3] = h3;
  lo[i * 4 + 0] = __float2bfloat16(v.x - __bfloat162float(h0));
  lo[i * 4 + 1] = __float2bfloat16(v.y - __bfloat162float(h1));
  lo[i * 4 + 2] = __float2bfloat16(v.z - __bfloat162float(h2));
  lo[i * 4 + 3] = __float2bfloat16(v.w - __bfloat162float(h3));
}

// ---------------------------------------------------------------------------
// L2b: scan (blocks 0,1) || fp32->bf16 splits (rest), all 1024-thread
// ---------------------------------------------------------------------------
__global__ __launch_bounds__(1024) void k_scansplit(
    const int* __restrict__ deg, int* __restrict__ row_off,
    const float* __restrict__ x, bf16_t* __restrict__ xh,
    bf16_t* __restrict__ xl, const float* __restrict__ W1_0,
    bf16_t* __restrict__ w1h0, bf16_t* __restrict__ w1l0,
    const float* __restrict__ W1_1, bf16_t* __restrict__ w1h1,
    bf16_t* __restrict__ w1l1, const float* __restrict__ W2_0,
    bf16_t* __restrict__ w2h0, bf16_t* __restrict__ w2l0,
    const float* __restrict__ W2_1, bf16_t* __restrict__ w2h1,
    bf16_t* __restrict__ w2l1) {
  int b = blockIdx.x;
  int tid = threadIdx.x;
  if (b < 2) {
    const int* tot = deg + b * NNODES;
    int* ro = row_off + b * (NNODES + 1);
    constexpr int PT = 20;  // 1024*20 >= NNODES
    __shared__ int wsum[16];
    int wid = tid >> 6, lane = tid & 63;
    int base_i = tid * PT;
    int v[PT];
    int s = 0;
#pragma unroll
    for (int q = 0; q < PT; ++q) {
      int i = base_i + q;
      v[q] = (i < NNODES) ? tot[i] : 0;
      s += v[q];
    }
    int xx = s;
#pragma unroll
    for (int o = 1; o < 64; o <<= 1) {
      int tv = __shfl_up(xx, o);
      if (lane >= o) xx += tv;
    }
    if (lane == 63) wsum[wid] = xx;
    __syncthreads();
    if (wid == 0) {
      int ws = (lane < 16) ? wsum[lane] : 0;
#pragma unroll
      for (int o = 1; o < 16; o <<= 1) {
        int tv = __shfl_up(ws, o);
        if (lane >= o) ws += tv;
      }
      if (lane < 16) wsum[lane] = ws;
    }
    __syncthreads();
    int run = (wid ? wsum[wid - 1] : 0) + (xx - s);
#pragma unroll
    for (int q = 0; q < PT; ++q) {
      int i = base_i + q;
      if (i < NNODES) ro[i] = run;
      run += v[q];
    }
    if (tid == 1023) ro[NNODES] = run;
    return;
  }
  b -= 2;
  if (b < SBX) { split_body(x, xh, xl, b * 1024 + tid, NNODES * 128 / 4); return; }
  b -= SBX;
  if (b < SBW1) { split_body(W1_0, w1h0, w1l0, b * 1024 + tid, 128 * 128 / 4); return; }
  b -= SBW1;
  if (b < SBW1) { split_body(W1_1, w1h1, w1l1, b * 1024 + tid, 128 * 128 / 4); return; }
  b -= SBW1;
  if (b < SBW2) { split_body(W2_0, w2h0, w2l0, b * 1024 + tid, 64 * 128 / 4); return; }
  b -= SBW2;
  split_body(W2_1, w2h1, w2l1, b * 1024 + tid, 64 * 128 / 4);
}

// ---------------------------------------------------------------------------
// scatter body (atomic-free): global slot = row_off[dst] + chunk base + rank
// ---------------------------------------------------------------------------
__device__ inline void scatter_body(int bb, int t, const int* src0,
                                    const int* dst0, const int* src1,
                                    const int* dst1, const u16* pos0,
                                    const u16* pos1, const int* row_off,
                                    const u16* cnt, u16* srt0, u16* srt1) {
  const int* src = t ? src1 : src0;
  const int* dst = t ? dst1 : dst0;
  const u16* pos = t ? pos1 : pos0;
  const int* ro = row_off + t * (NNODES + 1);
  u16* srt = t ? srt1 : srt0;
  int i = bb * 256 + threadIdx.x;
  if (i < NEDGES) {
    int dd = dst[i];
    int chunk = i / CHUNKE;
    int base = cnt[(size_t)(t * NB + chunk) * NNODES + dd];
    srt[ro[dd] + base + (int)pos[i]] = (u16)src[i];
  }
}

// ---------------------------------------------------------------------------
// MFMA GEMM, split-bf16 3-term, fp32 accumulate, fused rowdot epilogue.
// ---------------------------------------------------------------------------
template <int F>
__device__ inline void gemm_body(
    int bx, int t, const bf16_t* Xh, const bf16_t* Xl, const bf16_t* Wh0,
    const bf16_t* Wl0, const bf16_t* Wh1, const bf16_t* Wl1, const float* b0p,
    const float* b1p, const float* a0p, const float* a1p, bf16_t* Y0,
    bf16_t* Y1, float* al0, float* ar0, float* al1, float* ar1, int nrows) {
  constexpr int NT = F / 16;
  const bf16_t* Wgh = t ? Wh1 : Wh0;
  const bf16_t* Wgl = t ? Wl1 : Wl0;
  const float* bias = t ? b1p : b0p;
  const float* av = t ? a1p : a0p;
  bf16_t* Y = t ? Y1 : Y0;
  float* al = t ? al1 : al0;
  float* ar = t ? ar1 : ar0;

  int wid = threadIdx.x >> 6, lane = threadIdx.x & 63;
  int row0 = bx * 64 + wid * 16;
  int cl = lane & 15, g4 = lane >> 4;
  int rAc = min(row0 + cl, nrows - 1);

  f32x4 acc[NT] = {};

#pragma unroll
  for (int ks = 0; ks < 4; ++ks) {
    int k0 = ks * 32 + g4 * 8;
    bf16x8 Ah = *(const bf16x8*)&Xh[(size_t)rAc * 128 + k0];
    bf16x8 Al = *(const bf16x8*)&Xl[(size_t)rAc * 128 + k0];
#pragma unroll
    for (int nt = 0; nt < NT; ++nt) {
      size_t off = (size_t)(nt * 16 + cl) * 128 + k0;
      bf16x8 Bh = *(const bf16x8*)&Wgh[off];
      bf16x8 Bl = *(const bf16x8*)&Wgl[off];
      acc[nt] = __builtin_amdgcn_mfma_f32_16x16x32_bf16(Ah, Bh, acc[nt], 0, 0, 0);
      acc[nt] = __builtin_amdgcn_mfma_f32_16x16x32_bf16(Ah, Bl, acc[nt], 0, 0, 0);
      acc[nt] = __builtin_amdgcn_mfma_f32_16x16x32_bf16(Al, Bh, acc[nt], 0, 0, 0);
    }
  }

  // C/D layout: col = nt*16+cl, row = row0 + g4*4 + j   [m89/m91]
  float pl[4] = {}, pr[4] = {};
#pragma unroll
  for (int nt = 0; nt < NT; ++nt) {
    int c = nt * 16 + cl;
    float bv = bias[c], aL = av[c], aR = av[F + c];
#pragma unroll
    for (int j = 0; j < 4; ++j) {
      int r = row0 + g4 * 4 + j;
      float v = acc[nt][j] + bv;
      if (r < nrows) Y[(size_t)r * F + c] = __float2bfloat16(v);
      pl[j] += v * aL;
      pr[j] += v * aR;
    }
  }
#pragma unroll
  for (int j = 0; j < 4; ++j) {
    float sl = pl[j], sr = pr[j];
#pragma unroll
    for (int o = 8; o; o >>= 1) {
      sl += __shfl_xor(sl, o);
      sr += __shfl_xor(sr, o);
    }
    int r = row0 + g4 * 4 + j;
    if (cl == 0 && r < nrows) {
      al[r] = sl;
      ar[r] = sr;
    }
  }
}

// ---------------------------------------------------------------------------
// L3: gemm1 (both etypes, MFMA-bound, blocks first) || scatter (latency)
// ---------------------------------------------------------------------------
__global__ __launch_bounds__(256) void k_mid(
    const bf16_t* __restrict__ xh, const bf16_t* __restrict__ xl,
    const bf16_t* __restrict__ w1h0, const bf16_t* __restrict__ w1l0,
    const bf16_t* __restrict__ w1h1, const bf16_t* __restrict__ w1l1,
    const float* __restrict__ b1_0, const float* __restrict__ b1_1,
    const float* __restrict__ a1_0, const float* __restrict__ a1_1,
    bf16_t* __restrict__ Whb_0, bf16_t* __restrict__ Whb_1,
    float* __restrict__ alA, float* __restrict__ arA, float* __restrict__ alB,
    float* __restrict__ arB, const int* __restrict__ src0,
    const int* __restrict__ dst0, const int* __restrict__ src1,
    const int* __restrict__ dst1, const u16* __restrict__ pos0,
    const u16* __restrict__ pos1, const int* __restrict__ row_off,
    const u16* __restrict__ cnt, u16* __restrict__ srt0,
    u16* __restrict__ srt1) {
  int b = blockIdx.x;
  if (b < 2 * GB) {
    gemm_body<128>(b >= GB ? b - GB : b, b >= GB, xh, xl, w1h0, w1l0, w1h1,
                   w1l1, b1_0, b1_1, a1_0, a1_1, Whb_0, Whb_1, alA, arA, alB,
                   arB, NNODES);
    return;
  }
  b -= 2 * GB;
  scatter_body(b >= HB ? b - HB : b, b >= HB, src0, dst0, src1, dst1, pos0,
               pos1, row_off, cnt, srt0, srt1);
}

// ---------------------------------------------------------------------------
// L5: gemm2 wrapper
// ---------------------------------------------------------------------------
__global__ __launch_bounds__(256) void k_gemm64(
    const bf16_t* __restrict__ Xh, const bf16_t* __restrict__ Xl,
    const bf16_t* __restrict__ w2h0, const bf16_t* __restrict__ w2l0,
    const bf16_t* __restrict__ w2h1, const bf16_t* __restrict__ w2l1,
    const float* __restrict__ b2_0, const float* __restrict__ b2_1,
    const float* __restrict__ a2_0, const float* __restrict__ a2_1,
    bf16_t* __restrict__ Y0, bf16_t* __restrict__ Y1, float* __restrict__ al0,
    float* __restrict__ ar0, float* __restrict__ al1,
    float* __restrict__ ar1) {
  gemm_body<64>(blockIdx.x, blockIdx.y, Xh, Xl, w2h0, w2l0, w2h1, w2l1, b2_0,
                b2_1, a2_0, a2_1, Y0, Y1, al0, ar0, al1, ar1, NNODES);
}

// ---------------------------------------------------------------------------
// Fused dual-etype aggregation, single-pass softmax, bf16 gather.
// 4x-unrolled edge loop: 16 rows in flight per wave (gather latency hiding).
// ---------------------------------------------------------------------------
template <int F, int OMODE>
__global__ __launch_bounds__(256) void k_agg2(
    const int* __restrict__ row_off, const u16* __restrict__ srt0,
    const u16* __restrict__ srt1, const float* __restrict__ al0,
    const float* __restrict__ ar0, const float* __restrict__ al1,
    const float* __restrict__ ar1, const bf16_t* __restrict__ Wg0,
    const bf16_t* __restrict__ Wg1, float* __restrict__ H,
    bf16_t* __restrict__ Hh, bf16_t* __restrict__ Hl, int n) {
  constexpr int LPR = (F * 2) / 16;  // lanes per row (16B per lane)
  constexpr int NGR = 64 / LPR;      // edge groups per wave
  constexpr int VE = F / LPR;        // elements per lane (= 8)
  int wid = threadIdx.x >> 6, lane = threadIdx.x & 63;
  int d = blockIdx.x * 4 + wid;
  if (d >= n) return;
  int g = lane / LPR, cl = lane % LPR;
  float acc[VE] = {};

#pragma unroll
  for (int t = 0; t < 2; ++t) {
    const int* ro = row_off + t * (n + 1);
    const u16* srt = t ? srt1 : srt0;
    const float* al = t ? al1 : al0;
    const float* ar = t ? ar1 : ar0;
    const bf16_t* Wg = t ? Wg1 : Wg0;
    int beg = ro[d], end = ro[d + 1];
    if (beg == end) continue;
    float ard = ar[d];

    float denT = 0.f;
    float accT[VE] = {};
    int j = beg + g;
    // 4x unrolled: 4 rows in flight per lane (16 per wave)
    for (; j + 3 * NGR < end; j += 4 * NGR) {
      int s0 = srt[j], s1 = srt[j + NGR], s2 = srt[j + 2 * NGR],
          s3 = srt[j + 3 * NGR];
      float e0 = fminf(LRELU(al[s0] + ard), 70.f);
      float e1 = fminf(LRELU(al[s1] + ard), 70.f);
      float e2 = fminf(LRELU(al[s2] + ard), 70.f);
      float e3 = fminf(LRELU(al[s3] + ard), 70.f);
      float w0 = __expf(e0), w1 = __expf(e1), w2 = __expf(e2), w3 = __expf(e3);
      denT += (w0 + w1) + (w2 + w3);
      bf16x8 r0 = *(const bf16x8*)&Wg[(size_t)s0 * F + cl * 8];
      bf16x8 r1 = *(const bf16x8*)&Wg[(size_t)s1 * F + cl * 8];
      bf16x8 r2 = *(const bf16x8*)&Wg[(size_t)s2 * F + cl * 8];
      bf16x8 r3 = *(const bf16x8*)&Wg[(size_t)s3 * F + cl * 8];
#pragma unroll
      for (int v = 0; v < VE; ++v)
        accT[v] += (w0 * bf2f(r0[v]) + w1 * bf2f(r1[v])) +
                   (w2 * bf2f(r2[v]) + w3 * bf2f(r3[v]));
    }
    for (; j < end; j += NGR) {
      int s0 = srt[j];
      float e0 = fminf(LRELU(al[s0] + ard), 70.f);
      float w0 = __expf(e0);
      denT += w0;
      bf16x8 r0 = *(const bf16x8*)&Wg[(size_t)s0 * F + cl * 8];
#pragma unroll
      for (int v = 0; v < VE; ++v) accT[v] += w0 * bf2f(r0[v]);
    }

#pragma unroll
    for (int o = 32; o >= LPR; o >>= 1) {
      denT += __shfl_xor(denT, o);
#pragma unroll
      for (int v = 0; v < VE; ++v) accT[v] += __shfl_xor(accT[v], o);
    }
    float rden = 1.f / denT;
#pragma unroll
    for (int v = 0; v < VE; ++v) acc[v] += accT[v] * rden;
  }

  if (g == 0) {
    if (OMODE == 0) {
#pragma unroll
      for (int q = 0; q < VE; q += 4) {
        float4 o4 = make_float4(acc[q], acc[q + 1], acc[q + 2], acc[q + 3]);
        *(float4*)&H[(size_t)d * F + cl * VE + q] = o4;
      }
    } else {
      bf16x8 hv, lv;
#pragma unroll
      for (int q = 0; q < VE; ++q) {
        float v = LRELU(acc[q]);
        bf16_t h = __float2bfloat16(v);
        bf16_t l = __float2bfloat16(v - __bfloat162float(h));
        short hb, lb;
        __builtin_memcpy(&hb, &h, 2);
        __builtin_memcpy(&lb, &l, 2);
        hv[q] = hb;
        lv[q] = lb;
      }
      *(bf16x8*)&Hh[(size_t)d * F + cl * 8] = hv;
      *(bf16x8*)&Hl[(size_t)d * F + cl * 8] = lv;
    }
  }
}

// ---------------------------------------------------------------------------
// launch
// ---------------------------------------------------------------------------
extern "C" void kernel_launch(void* const* d_in, const int* in_sizes, int n_in,
                              void* d_out, int out_size, void* d_ws,
                              size_t ws_size, hipStream_t stream) {
  const float* x    = (const float*)d_in[0];
  const float* W1_0 = (const float*)d_in[1];
  const float* b1_0 = (const float*)d_in[2];
  const float* a1_0 = (const float*)d_in[3];
  const float* W1_1 = (const float*)d_in[4];
  const float* b1_1 = (const float*)d_in[5];
  const float* a1_1 = (const float*)d_in[6];
  const float* W2_0 = (const float*)d_in[7];
  const float* b2_0 = (const float*)d_in[8];
  const float* a2_0 = (const float*)d_in[9];
  const float* W2_1 = (const float*)d_in[10];
  const float* b2_1 = (const float*)d_in[11];
  const float* a2_1 = (const float*)d_in[12];
  const int* src0 = (const int*)d_in[13];
  const int* dst0 = (const int*)d_in[14];
  const int* src1 = (const int*)d_in[15];
  const int* dst1 = (const int*)d_in[16];
  float* out = (float*)d_out;

  const int N = NNODES, E = NEDGES;

  char* w = (char*)d_ws;
  auto alloc = [&](size_t bytes) -> char* {
    char* p = w;
    w += (bytes + 255) & ~(size_t)255;
    return p;
  };
  int* row_off = (int*)alloc(2 * (N + 1) * sizeof(int));
  int* deg     = (int*)alloc(2 * N * sizeof(int));
  u16* cnt     = (u16*)alloc((size_t)2 * NB * N * 2);
  u16* pos0    = (u16*)alloc((size_t)E * 2);
  u16* pos1    = (u16*)alloc((size_t)E * 2);
  u16* srt0    = (u16*)alloc((size_t)E * 2);
  u16* srt1    = (u16*)alloc((size_t)E * 2);
  bf16_t* xh   = (bf16_t*)alloc((size_t)N * 128 * 2);
  bf16_t* xl   = (bf16_t*)alloc((size_t)N * 128 * 2);
  bf16_t* Whb_0 = (bf16_t*)alloc((size_t)N * 128 * 2);
  bf16_t* Whb_1 = (bf16_t*)alloc((size_t)N * 128 * 2);
  bf16_t* h1h  = (bf16_t*)alloc((size_t)N * 128 * 2);
  bf16_t* h1l  = (bf16_t*)alloc((size_t)N * 128 * 2);
  bf16_t* w1h0 = (bf16_t*)alloc(128 * 128 * 2);
  bf16_t* w1l0 = (bf16_t*)alloc(128 * 128 * 2);
  bf16_t* w1h1 = (bf16_t*)alloc(128 * 128 * 2);
  bf16_t* w1l1 = (bf16_t*)alloc(128 * 128 * 2);
  bf16_t* w2h0 = (bf16_t*)alloc(64 * 128 * 2);
  bf16_t* w2l0 = (bf16_t*)alloc(64 * 128 * 2);
  bf16_t* w2h1 = (bf16_t*)alloc(64 * 128 * 2);
  bf16_t* w2l1 = (bf16_t*)alloc(64 * 128 * 2);
  bf16_t* Wh2b_0 = (bf16_t*)alloc((size_t)N * 64 * 2);
  bf16_t* Wh2b_1 = (bf16_t*)alloc((size_t)N * 64 * 2);
  float* alA   = (float*)alloc(N * sizeof(float));
  float* arA   = (float*)alloc(N * sizeof(float));
  float* alB   = (float*)alloc(N * sizeof(float));
  float* arB   = (float*)alloc(N * sizeof(float));
  (void)ws_size;

  // L1: LDS chunk histogram (256 blocks x 1024, no global atomics)
  k_hist<<<2 * NB, 1024, 0, stream>>>(dst0, dst1, cnt, pos0, pos1);
  // L2a: combine chunk counts -> bases (in cnt) + deg totals
  k_combine<<<(2 * N + 255) / 256, 256, 0, stream>>>(cnt, deg);
  // L2b: scan (2 blocks) || splits
  int ssg = 2 + SBX + 2 * SBW1 + 2 * SBW2;
  k_scansplit<<<ssg, 1024, 0, stream>>>(deg, row_off, x, xh, xl, W1_0, w1h0,
                                        w1l0, W1_1, w1h1, w1l1, W2_0, w2h0,
                                        w2l0, W2_1, w2h1, w2l1);
  // L3: gemm1 || scatter
  int midg = 2 * GB + 2 * HB;
  k_mid<<<midg, 256, 0, stream>>>(xh, xl, w1h0, w1l0, w1h1, w1l1, b1_0, b1_1,
                                  a1_0, a1_1, Whb_0, Whb_1, alA, arA, alB,
                                  arB, src0, dst0, src1, dst1, pos0, pos1,
                                  row_off, cnt, srt0, srt1);
  // L4: agg layer 1 (F=128, bf16 gather, lrelu+split-bf16 out)
  int ngrid4 = (N + 3) / 4;
  k_agg2<128, 1><<<ngrid4, 256, 0, stream>>>(
      row_off, srt0, srt1, alA, arA, alB, arB, Whb_0, Whb_1, nullptr, h1h,
      h1l, N);
  // L5: gemm2 (F=64)
  k_gemm64<<<dim3(GB, 2), 256, 0, stream>>>(h1h, h1l, w2h0, w2l0, w2h1, w2l1,
                                            b2_0, b2_1, a2_0, a2_1, Wh2b_0,
                                            Wh2b_1, alA, arA, alB, arB);
  // L6: agg layer 2 (F=64, bf16 gather, fp32 out)
  k_agg2<64, 0><<<ngrid4, 256, 0, stream>>>(
      row_off, srt0, srt1, alA, arA, alB, arB, Wh2b_0, Wh2b_1, out, nullptr,
      nullptr, N);
}

// Round 13
// 223.844 us; speedup vs baseline: 1.0701x; 1.0701x over previous
//
#include <hip/hip_runtime.h>
#include <hip/hip_bf16.h>

#define NNODES 20000
#define NEDGES 500000
#define LRELU(v) ((v) > 0.f ? (v) : (v) * 0.01f)

using bf16_t = __hip_bfloat16;
typedef unsigned short u16;
typedef unsigned int u32;
typedef __attribute__((ext_vector_type(8))) short bf16x8;  // 8 bf16 (4 VGPRs)
typedef __attribute__((ext_vector_type(4))) float f32x4;

__device__ inline float bf2f(short u) {
  u32 i = ((u32)(u16)u) << 16;
  float f;
  __builtin_memcpy(&f, &i, 4);
  return f;
}

// block-count constants
constexpr int NB = 64;                               // hist chunks per etype
constexpr int CHUNKE = (NEDGES + NB - 1) / NB;       // 7813 edges per hist block
constexpr int HB = (NEDGES + 255) / 256;             // scatter blocks per etype
constexpr int GB = (NNODES + 63) / 64;               // gemm blocks per etype
// 1024-thread split block counts
constexpr int SBX = NNODES * 128 / 4 / 1024;         // 625
constexpr int SBW1 = 128 * 128 / 4 / 1024;           // 4
constexpr int SBW2 = 64 * 128 / 4 / 1024;            // 2

// ---------------------------------------------------------------------------
// L1: LDS chunk histogram, 2*NB blocks (etype t = b/NB, chunk c = b%NB).
// pos[i] = rank of edge i within (chunk, dst). cnt[t][c][dst] = chunk count
// (plain u16 stores, NO global atomics).
// ---------------------------------------------------------------------------
__global__ __launch_bounds__(1024) void k_hist(const int* __restrict__ dst0,
                                               const int* __restrict__ dst1,
                                               u16* __restrict__ cnt,
                                               u16* __restrict__ pos0,
                                               u16* __restrict__ pos1) {
  __shared__ u32 hist[NNODES / 2];  // 2 x u16 packed per word
  int b = blockIdx.x;
  int t = b >> 6, c = b & 63;       // NB = 64
  const int* dst = t ? dst1 : dst0;
  u16* pos = t ? pos1 : pos0;
  u16* cb = cnt + (size_t)(t * NB + c) * NNODES;
  int tid = threadIdx.x;

  for (int i = tid; i < NNODES / 2; i += 1024) hist[i] = 0;
  __syncthreads();

  int beg = c * CHUNKE, end = min(NEDGES, beg + CHUNKE);
  for (int i = beg + tid; i < end; i += 1024) {
    int d = dst[i];
    int sh = (d & 1) * 16;
    u32 old = atomicAdd(&hist[d >> 1], 1u << sh);
    pos[i] = (u16)((old >> sh) & 0xFFFFu);  // rank within (chunk, dst)
  }
  __syncthreads();

  for (int i = tid; i < NNODES / 2; i += 1024)
    *(u32*)&cb[2 * i] = hist[i];  // two u16 counts per 4B store
}

// ---------------------------------------------------------------------------
// L2a: combine. One thread per (t,dst): exclusive prefix over the NB chunk
// counts (written back into cnt as bases); total -> deg. All coalesced.
// ---------------------------------------------------------------------------
__global__ __launch_bounds__(256) void k_combine(u16* __restrict__ cnt,
                                                 int* __restrict__ deg) {
  int i = blockIdx.x * 256 + threadIdx.x;  // i in [0, 2*NNODES)
  if (i >= 2 * NNODES) return;
  int t = i / NNODES, dd = i - t * NNODES;
  int run = 0;
#pragma unroll 8
  for (int g = 0; g < NB; ++g) {
    size_t idx = (size_t)(t * NB + g) * NNODES + dd;
    int cv = cnt[idx];
    cnt[idx] = (u16)run;
    run += cv;
  }
  deg[i] = run;
}

// ---------------------------------------------------------------------------
// split body (1024-thread blocks)
// ---------------------------------------------------------------------------
__device__ inline void split_body(const float* in, bf16_t* hi, bf16_t* lo,
                                  int i, int n4) {
  if (i >= n4) return;
  float4 v = *(const float4*)&in[i * 4];
  bf16_t h0 = __float2bfloat16(v.x), h1 = __float2bfloat16(v.y);
  bf16_t h2 = __float2bfloat16(v.z), h3 = __float2bfloat16(v.w);
  hi[i * 4 + 0] = h0;
  hi[i * 4 + 1] = h1;
  hi[i * 4 + 2] = h2;
  hi[i * 4 + 3] = h3;
  lo[i * 4 + 0] = __float2bfloat16(v.x - __bfloat162float(h0));
  lo[i * 4 + 1] = __float2bfloat16(v.y - __bfloat162float(h1));
  lo[i * 4 + 2] = __float2bfloat16(v.z - __bfloat162float(h2));
  lo[i * 4 + 3] = __float2bfloat16(v.w - __bfloat162float(h3));
}

// ---------------------------------------------------------------------------
// L2b: scan (blocks 0,1) || fp32->bf16 splits (rest), all 1024-thread
// ---------------------------------------------------------------------------
__global__ __launch_bounds__(1024) void k_scansplit(
    const int* __restrict__ deg, int* __restrict__ row_off,
    const float* __restrict__ x, bf16_t* __restrict__ xh,
    bf16_t* __restrict__ xl, const float* __restrict__ W1_0,
    bf16_t* __restrict__ w1h0, bf16_t* __restrict__ w1l0,
    const float* __restrict__ W1_1, bf16_t* __restrict__ w1h1,
    bf16_t* __restrict__ w1l1, const float* __restrict__ W2_0,
    bf16_t* __restrict__ w2h0, bf16_t* __restrict__ w2l0,
    const float* __restrict__ W2_1, bf16_t* __restrict__ w2h1,
    bf16_t* __restrict__ w2l1) {
  int b = blockIdx.x;
  int tid = threadIdx.x;
  if (b < 2) {
    const int* tot = deg + b * NNODES;
    int* ro = row_off + b * (NNODES + 1);
    constexpr int PT = 20;  // 1024*20 >= NNODES
    __shared__ int wsum[16];
    int wid = tid >> 6, lane = tid & 63;
    int base_i = tid * PT;
    int v[PT];
    int s = 0;
#pragma unroll
    for (int q = 0; q < PT; ++q) {
      int i = base_i + q;
      v[q] = (i < NNODES) ? tot[i] : 0;
      s += v[q];
    }
    int xx = s;
#pragma unroll
    for (int o = 1; o < 64; o <<= 1) {
      int tv = __shfl_up(xx, o);
      if (lane >= o) xx += tv;
    }
    if (lane == 63) wsum[wid] = xx;
    __syncthreads();
    if (wid == 0) {
      int ws = (lane < 16) ? wsum[lane] : 0;
#pragma unroll
      for (int o = 1; o < 16; o <<= 1) {
        int tv = __shfl_up(ws, o);
        if (lane >= o) ws += tv;
      }
      if (lane < 16) wsum[lane] = ws;
    }
    __syncthreads();
    int run = (wid ? wsum[wid - 1] : 0) + (xx - s);
#pragma unroll
    for (int q = 0; q < PT; ++q) {
      int i = base_i + q;
      if (i < NNODES) ro[i] = run;
      run += v[q];
    }
    if (tid == 1023) ro[NNODES] = run;
    return;
  }
  b -= 2;
  if (b < SBX) { split_body(x, xh, xl, b * 1024 + tid, NNODES * 128 / 4); return; }
  b -= SBX;
  if (b < SBW1) { split_body(W1_0, w1h0, w1l0, b * 1024 + tid, 128 * 128 / 4); return; }
  b -= SBW1;
  if (b < SBW1) { split_body(W1_1, w1h1, w1l1, b * 1024 + tid, 128 * 128 / 4); return; }
  b -= SBW1;
  if (b < SBW2) { split_body(W2_0, w2h0, w2l0, b * 1024 + tid, 64 * 128 / 4); return; }
  b -= SBW2;
  split_body(W2_1, w2h1, w2l1, b * 1024 + tid, 64 * 128 / 4);
}

// ---------------------------------------------------------------------------
// scatter body (atomic-free): global slot = row_off[dst] + chunk base + rank
// ---------------------------------------------------------------------------
__device__ inline void scatter_body(int bb, int t, const int* src0,
                                    const int* dst0, const int* src1,
                                    const int* dst1, const u16* pos0,
                                    const u16* pos1, const int* row_off,
                                    const u16* cnt, u16* srt0, u16* srt1) {
  const int* src = t ? src1 : src0;
  const int* dst = t ? dst1 : dst0;
  const u16* pos = t ? pos1 : pos0;
  const int* ro = row_off + t * (NNODES + 1);
  u16* srt = t ? srt1 : srt0;
  int i = bb * 256 + threadIdx.x;
  if (i < NEDGES) {
    int dd = dst[i];
    int chunk = i / CHUNKE;
    int base = cnt[(size_t)(t * NB + chunk) * NNODES + dd];
    srt[ro[dd] + base + (int)pos[i]] = (u16)src[i];
  }
}

// ---------------------------------------------------------------------------
// MFMA GEMM, split-bf16 3-term, fp32 accumulate, fused rowdot epilogue.
// ---------------------------------------------------------------------------
template <int F>
__device__ inline void gemm_body(
    int bx, int t, const bf16_t* Xh, const bf16_t* Xl, const bf16_t* Wh0,
    const bf16_t* Wl0, const bf16_t* Wh1, const bf16_t* Wl1, const float* b0p,
    const float* b1p, const float* a0p, const float* a1p, bf16_t* Y0,
    bf16_t* Y1, float* al0, float* ar0, float* al1, float* ar1, int nrows) {
  constexpr int NT = F / 16;
  const bf16_t* Wgh = t ? Wh1 : Wh0;
  const bf16_t* Wgl = t ? Wl1 : Wl0;
  const float* bias = t ? b1p : b0p;
  const float* av = t ? a1p : a0p;
  bf16_t* Y = t ? Y1 : Y0;
  float* al = t ? al1 : al0;
  float* ar = t ? ar1 : ar0;

  int wid = threadIdx.x >> 6, lane = threadIdx.x & 63;
  int row0 = bx * 64 + wid * 16;
  int cl = lane & 15, g4 = lane >> 4;
  int rAc = min(row0 + cl, nrows - 1);

  f32x4 acc[NT] = {};

#pragma unroll
  for (int ks = 0; ks < 4; ++ks) {
    int k0 = ks * 32 + g4 * 8;
    bf16x8 Ah = *(const bf16x8*)&Xh[(size_t)rAc * 128 + k0];
    bf16x8 Al = *(const bf16x8*)&Xl[(size_t)rAc * 128 + k0];
#pragma unroll
    for (int nt = 0; nt < NT; ++nt) {
      size_t off = (size_t)(nt * 16 + cl) * 128 + k0;
      bf16x8 Bh = *(const bf16x8*)&Wgh[off];
      bf16x8 Bl = *(const bf16x8*)&Wgl[off];
      acc[nt] = __builtin_amdgcn_mfma_f32_16x16x32_bf16(Ah, Bh, acc[nt], 0, 0, 0);
      acc[nt] = __builtin_amdgcn_mfma_f32_16x16x32_bf16(Ah, Bl, acc[nt], 0, 0, 0);
      acc[nt] = __builtin_amdgcn_mfma_f32_16x16x32_bf16(Al, Bh, acc[nt], 0, 0, 0);
    }
  }

  // C/D layout: col = nt*16+cl, row = row0 + g4*4 + j   [m89/m91]
  float pl[4] = {}, pr[4] = {};
#pragma unroll
  for (int nt = 0; nt < NT; ++nt) {
    int c = nt * 16 + cl;
    float bv = bias[c], aL = av[c], aR = av[F + c];
#pragma unroll
    for (int j = 0; j < 4; ++j) {
      int r = row0 + g4 * 4 + j;
      float v = acc[nt][j] + bv;
      if (r < nrows) Y[(size_t)r * F + c] = __float2bfloat16(v);
      pl[j] += v * aL;
      pr[j] += v * aR;
    }
  }
#pragma unroll
  for (int j = 0; j < 4; ++j) {
    float sl = pl[j], sr = pr[j];
#pragma unroll
    for (int o = 8; o; o >>= 1) {
      sl += __shfl_xor(sl, o);
      sr += __shfl_xor(sr, o);
    }
    int r = row0 + g4 * 4 + j;
    if (cl == 0 && r < nrows) {
      al[r] = sl;
      ar[r] = sr;
    }
  }
}

// ---------------------------------------------------------------------------
// L3: gemm1 (both etypes, MFMA-bound, blocks first) || scatter (latency)
// ---------------------------------------------------------------------------
__global__ __launch_bounds__(256) void k_mid(
    const bf16_t* __restrict__ xh, const bf16_t* __restrict__ xl,
    const bf16_t* __restrict__ w1h0, const bf16_t* __restrict__ w1l0,
    const bf16_t* __restrict__ w1h1, const bf16_t* __restrict__ w1l1,
    const float* __restrict__ b1_0, const float* __restrict__ b1_1,
    const float* __restrict__ a1_0, const float* __restrict__ a1_1,
    bf16_t* __restrict__ Whb_0, bf16_t* __restrict__ Whb_1,
    float* __restrict__ alA, float* __restrict__ arA, float* __restrict__ alB,
    float* __restrict__ arB, const int* __restrict__ src0,
    const int* __restrict__ dst0, const int* __restrict__ src1,
    const int* __restrict__ dst1, const u16* __restrict__ pos0,
    const u16* __restrict__ pos1, const int* __restrict__ row_off,
    const u16* __restrict__ cnt, u16* __restrict__ srt0,
    u16* __restrict__ srt1) {
  int b = blockIdx.x;
  if (b < 2 * GB) {
    gemm_body<128>(b >= GB ? b - GB : b, b >= GB, xh, xl, w1h0, w1l0, w1h1,
                   w1l1, b1_0, b1_1, a1_0, a1_1, Whb_0, Whb_1, alA, arA, alB,
                   arB, NNODES);
    return;
  }
  b -= 2 * GB;
  scatter_body(b >= HB ? b - HB : b, b >= HB, src0, dst0, src1, dst1, pos0,
               pos1, row_off, cnt, srt0, srt1);
}

// ---------------------------------------------------------------------------
// L5: gemm2 wrapper
// ---------------------------------------------------------------------------
__global__ __launch_bounds__(256) void k_gemm64(
    const bf16_t* __restrict__ Xh, const bf16_t* __restrict__ Xl,
    const bf16_t* __restrict__ w2h0, const bf16_t* __restrict__ w2l0,
    const bf16_t* __restrict__ w2h1, const bf16_t* __restrict__ w2l1,
    const float* __restrict__ b2_0, const float* __restrict__ b2_1,
    const float* __restrict__ a2_0, const float* __restrict__ a2_1,
    bf16_t* __restrict__ Y0, bf16_t* __restrict__ Y1, float* __restrict__ al0,
    float* __restrict__ ar0, float* __restrict__ al1,
    float* __restrict__ ar1) {
  gemm_body<64>(blockIdx.x, blockIdx.y, Xh, Xl, w2h0, w2l0, w2h1, w2l1, b2_0,
                b2_1, a2_0, a2_1, Y0, Y1, al0, ar0, al1, ar1, NNODES);
}

// ---------------------------------------------------------------------------
// Fused dual-etype aggregation, single-pass softmax, bf16 gather.
// ---------------------------------------------------------------------------
template <int F, int OMODE>
__global__ __launch_bounds__(256) void k_agg2(
    const int* __restrict__ row_off, const u16* __restrict__ srt0,
    const u16* __restrict__ srt1, const float* __restrict__ al0,
    const float* __restrict__ ar0, const float* __restrict__ al1,
    const float* __restrict__ ar1, const bf16_t* __restrict__ Wg0,
    const bf16_t* __restrict__ Wg1, float* __restrict__ H,
    bf16_t* __restrict__ Hh, bf16_t* __restrict__ Hl, int n) {
  constexpr int LPR = (F * 2) / 16;  // lanes per row (16B per lane)
  constexpr int NGR = 64 / LPR;      // edge groups per wave
  constexpr int VE = F / LPR;        // elements per lane (= 8)
  int wid = threadIdx.x >> 6, lane = threadIdx.x & 63;
  int d = blockIdx.x * 4 + wid;
  if (d >= n) return;
  int g = lane / LPR, cl = lane % LPR;
  float acc[VE] = {};

#pragma unroll
  for (int t = 0; t < 2; ++t) {
    const int* ro = row_off + t * (n + 1);
    const u16* srt = t ? srt1 : srt0;
    const float* al = t ? al1 : al0;
    const float* ar = t ? ar1 : ar0;
    const bf16_t* Wg = t ? Wg1 : Wg0;
    int beg = ro[d], end = ro[d + 1];
    if (beg == end) continue;
    float ard = ar[d];

    float denT = 0.f;
    float accT[VE] = {};
    int j = beg + g;
    for (; j + NGR < end; j += 2 * NGR) {
      int s0 = srt[j], s1 = srt[j + NGR];
      float e0 = fminf(LRELU(al[s0] + ard), 70.f);
      float e1 = fminf(LRELU(al[s1] + ard), 70.f);
      float w0 = __expf(e0), w1 = __expf(e1);
      denT += w0 + w1;
      bf16x8 r0 = *(const bf16x8*)&Wg[(size_t)s0 * F + cl * 8];
      bf16x8 r1 = *(const bf16x8*)&Wg[(size_t)s1 * F + cl * 8];
#pragma unroll
      for (int v = 0; v < VE; ++v)
        accT[v] += w0 * bf2f(r0[v]) + w1 * bf2f(r1[v]);
    }
    if (j < end) {
      int s0 = srt[j];
      float e0 = fminf(LRELU(al[s0] + ard), 70.f);
      float w0 = __expf(e0);
      denT += w0;
      bf16x8 r0 = *(const bf16x8*)&Wg[(size_t)s0 * F + cl * 8];
#pragma unroll
      for (int v = 0; v < VE; ++v) accT[v] += w0 * bf2f(r0[v]);
    }

#pragma unroll
    for (int o = 32; o >= LPR; o >>= 1) {
      denT += __shfl_xor(denT, o);
#pragma unroll
      for (int v = 0; v < VE; ++v) accT[v] += __shfl_xor(accT[v], o);
    }
    float rden = 1.f / denT;
#pragma unroll
    for (int v = 0; v < VE; ++v) acc[v] += accT[v] * rden;
  }

  if (g == 0) {
    if (OMODE == 0) {
#pragma unroll
      for (int q = 0; q < VE; q += 4) {
        float4 o4 = make_float4(acc[q], acc[q + 1], acc[q + 2], acc[q + 3]);
        *(float4*)&H[(size_t)d * F + cl * VE + q] = o4;
      }
    } else {
      bf16x8 hv, lv;
#pragma unroll
      for (int q = 0; q < VE; ++q) {
        float v = LRELU(acc[q]);
        bf16_t h = __float2bfloat16(v);
        bf16_t l = __float2bfloat16(v - __bfloat162float(h));
        short hb, lb;
        __builtin_memcpy(&hb, &h, 2);
        __builtin_memcpy(&lb, &l, 2);
        hv[q] = hb;
        lv[q] = lb;
      }
      *(bf16x8*)&Hh[(size_t)d * F + cl * 8] = hv;
      *(bf16x8*)&Hl[(size_t)d * F + cl * 8] = lv;
    }
  }
}

// ---------------------------------------------------------------------------
// launch
// ---------------------------------------------------------------------------
extern "C" void kernel_launch(void* const* d_in, const int* in_sizes, int n_in,
                              void* d_out, int out_size, void* d_ws,
                              size_t ws_size, hipStream_t stream) {
  const float* x    = (const float*)d_in[0];
  const float* W1_0 = (const float*)d_in[1];
  const float* b1_0 = (const float*)d_in[2];
  const float* a1_0 = (const float*)d_in[3];
  const float* W1_1 = (const float*)d_in[4];
  const float* b1_1 = (const float*)d_in[5];
  const float* a1_1 = (const float*)d_in[6];
  const float* W2_0 = (const float*)d_in[7];
  const float* b2_0 = (const float*)d_in[8];
  const float* a2_0 = (const float*)d_in[9];
  const float* W2_1 = (const float*)d_in[10];
  const float* b2_1 = (const float*)d_in[11];
  const float* a2_1 = (const float*)d_in[12];
  const int* src0 = (const int*)d_in[13];
  const int* dst0 = (const int*)d_in[14];
  const int* src1 = (const int*)d_in[15];
  const int* dst1 = (const int*)d_in[16];
  float* out = (float*)d_out;

  const int N = NNODES, E = NEDGES;

  char* w = (char*)d_ws;
  auto alloc = [&](size_t bytes) -> char* {
    char* p = w;
    w += (bytes + 255) & ~(size_t)255;
    return p;
  };
  int* row_off = (int*)alloc(2 * (N + 1) * sizeof(int));
  int* deg     = (int*)alloc(2 * N * sizeof(int));
  u16* cnt     = (u16*)alloc((size_t)2 * NB * N * 2);
  u16* pos0    = (u16*)alloc((size_t)E * 2);
  u16* pos1    = (u16*)alloc((size_t)E * 2);
  u16* srt0    = (u16*)alloc((size_t)E * 2);
  u16* srt1    = (u16*)alloc((size_t)E * 2);
  bf16_t* xh   = (bf16_t*)alloc((size_t)N * 128 * 2);
  bf16_t* xl   = (bf16_t*)alloc((size_t)N * 128 * 2);
  bf16_t* Whb_0 = (bf16_t*)alloc((size_t)N * 128 * 2);
  bf16_t* Whb_1 = (bf16_t*)alloc((size_t)N * 128 * 2);
  bf16_t* h1h  = (bf16_t*)alloc((size_t)N * 128 * 2);
  bf16_t* h1l  = (bf16_t*)alloc((size_t)N * 128 * 2);
  bf16_t* w1h0 = (bf16_t*)alloc(128 * 128 * 2);
  bf16_t* w1l0 = (bf16_t*)alloc(128 * 128 * 2);
  bf16_t* w1h1 = (bf16_t*)alloc(128 * 128 * 2);
  bf16_t* w1l1 = (bf16_t*)alloc(128 * 128 * 2);
  bf16_t* w2h0 = (bf16_t*)alloc(64 * 128 * 2);
  bf16_t* w2l0 = (bf16_t*)alloc(64 * 128 * 2);
  bf16_t* w2h1 = (bf16_t*)alloc(64 * 128 * 2);
  bf16_t* w2l1 = (bf16_t*)alloc(64 * 128 * 2);
  bf16_t* Wh2b_0 = (bf16_t*)alloc((size_t)N * 64 * 2);
  bf16_t* Wh2b_1 = (bf16_t*)alloc((size_t)N * 64 * 2);
  float* alA   = (float*)alloc(N * sizeof(float));
  float* arA   = (float*)alloc(N * sizeof(float));
  float* alB   = (float*)alloc(N * sizeof(float));
  float* arB   = (float*)alloc(N * sizeof(float));
  (void)ws_size;

  // L1: LDS chunk histogram (128 blocks x 1024, no global atomics)
  k_hist<<<2 * NB, 1024, 0, stream>>>(dst0, dst1, cnt, pos0, pos1);
  // L2a: combine chunk counts -> bases (in cnt) + deg totals
  k_combine<<<(2 * N + 255) / 256, 256, 0, stream>>>(cnt, deg);
  // L2b: scan (2 blocks) || splits
  int ssg = 2 + SBX + 2 * SBW1 + 2 * SBW2;
  k_scansplit<<<ssg, 1024, 0, stream>>>(deg, row_off, x, xh, xl, W1_0, w1h0,
                                        w1l0, W1_1, w1h1, w1l1, W2_0, w2h0,
                                        w2l0, W2_1, w2h1, w2l1);
  // L3: gemm1 || scatter
  int midg = 2 * GB + 2 * HB;
  k_mid<<<midg, 256, 0, stream>>>(xh, xl, w1h0, w1l0, w1h1, w1l1, b1_0, b1_1,
                                  a1_0, a1_1, Whb_0, Whb_1, alA, arA, alB,
                                  arB, src0, dst0, src1, dst1, pos0, pos1,
                                  row_off, cnt, srt0, srt1);
  // L4: agg layer 1 (F=128, bf16 gather, lrelu+split-bf16 out)
  int ngrid4 = (N + 3) / 4;
  k_agg2<128, 1><<<ngrid4, 256, 0, stream>>>(
      row_off, srt0, srt1, alA, arA, alB, arB, Whb_0, Whb_1, nullptr, h1h,
      h1l, N);
  // L5: gemm2 (F=64)
  k_gemm64<<<dim3(GB, 2), 256, 0, stream>>>(h1h, h1l, w2h0, w2l0, w2h1, w2l1,
                                            b2_0, b2_1, a2_0, a2_1, Wh2b_0,
                                            Wh2b_1, alA, arA, alB, arB);
  // L6: agg layer 2 (F=64, bf16 gather, fp32 out)
  k_agg2<64, 0><<<ngrid4, 256, 0, stream>>>(
      row_off, srt0, srt1, alA, arA, alB, arB, Wh2b_0, Wh2b_1, out, nullptr,
      nullptr, N);
}